// Round 14
// baseline (113.264 us; speedup 1.0000x reference)
//
#include <hip/hip_runtime.h>
#include <math.h>

namespace {

constexpr int kRows = 4096;
constexpr int kNF   = 65;
constexpr int kNE   = 256;
constexpr int kNH   = 8;
constexpr int kNC   = 64;                  // kNF - 1 fields used
constexpr int kXRow = kNF * kNE;           // 16640 floats per x row
constexpr int kORow = (kNF + kNH) * kNE;   // 18688 floats per out row
constexpr int kRPB  = 2;                   // rows per block (grid 2048)

typedef float vf4 __attribute__((ext_vector_type(4)));  // asm/NT-compatible

// w2[t] = sum_k bw[t*256+k] * query[(t>>5)*256+k].  32 blocks x 256 threads.
__global__ __launch_bounds__(256) void w2_precompute(
    const float* __restrict__ bw, const float* __restrict__ query,
    float* __restrict__ w2) {
  const int o = threadIdx.x >> 5;          // 0..7: which of this block's outputs
  const int l = threadIdx.x & 31;          // 32 lanes per output
  const int t = blockIdx.x * 8 + o;
  const int h = t >> 5;
  const vf4* __restrict__ bp =
      reinterpret_cast<const vf4*>(bw + (size_t)t * 256 + l * 8);
  const vf4* __restrict__ qp =
      reinterpret_cast<const vf4*>(query + (size_t)h * 256 + l * 8);
  const vf4 b0 = bp[0], b1 = bp[1];
  const vf4 q0 = qp[0], q1 = qp[1];
  float acc = b0.x * q0.x + b0.y * q0.y + b0.z * q0.z + b0.w * q0.w
            + b1.x * q1.x + b1.y * q1.y + b1.z * q1.z + b1.w * q1.w;
  acc += __shfl_xor(acc, 1);
  acc += __shfl_xor(acc, 2);
  acc += __shfl_xor(acc, 4);
  acc += __shfl_xor(acc, 8);
  acc += __shfl_xor(acc, 16);
  if (l == 0) w2[t] = acc;
}

// One block = kRPB=2 consecutive rows (grid 2048), 512 threads = 8 waves.
// Round-13 config (99 us; clean: VGPR 36 = kreg+wq exactly, no scratch, no
// remat, conflicts ~0, VALUBusy 12.6%) + ONE isolated change: 2 rows/block.
// Rationale: occupancy 55% with nothing capping below 100% + 4096 short
// blocks retiring in ~99 us -> ~41 dispatches/us device-wide = dispatch/
// backfill marginal. 2048 blocks halves dispatch pressure while KEEPING a
// 4-blocks/CU backfill queue (round-11 failure was 1024 persistent = exactly
// 4/CU, zero backfill -> occupancy 38%). g-loop barrier safety as analyzed
// round 11: every shared buffer's next-row write sits behind a block-wide
// barrier that postdates all prior-row reads of it.
// Entmax: wave 0 only (round 12). NT stores for out (round 8). kreg pinned
// via asm (round 13). No min-waves hints (rounds 3-5: they force spills).
__global__ __launch_bounds__(512) void fused_row(
    const float* __restrict__ x, const float* __restrict__ w2g,
    const float* __restrict__ vals, float* __restrict__ out) {
  __shared__ float att_t[kNC * 9];        // [c][h] stride 9: conflict-free gather
  __shared__ float cw[kNC * kNH];         // [c][h], 2 KB
  __shared__ vf4 part[8 * 4 * 64];        // [slot][head4][equad], 32 KB (x2 passes)

  const int tid  = threadIdx.x;
  const int wv   = tid >> 6;
  const int lane = tid & 63;

  // Lane's w2 quad: head h = lane>>3, dims 4*(lane&7)..+3 (hoisted over rows).
  const vf4 wq = reinterpret_cast<const vf4*>(w2g)[lane];
  const vf4* __restrict__ cw4 = reinterpret_cast<const vf4*>(cw);
  const float* partf          = reinterpret_cast<const float*>(part);

#pragma unroll 1
  for (int g = 0; g < kRPB; ++g) {
    const int r = blockIdx.x * kRPB + g;
    const float* __restrict__ xrow = x + (size_t)r * kXRow;
    float* __restrict__ orow       = out + (size_t)r * kORow;
    const vf4* __restrict__ x4     = reinterpret_cast<const vf4*>(xrow);
    vf4* __restrict__ o4           = reinterpret_cast<vf4*>(orow);

    // ---- phase A: issue ALL loads first (9 outstanding vmem per wave), then
    //      copy -> out (NT) + att dot + 3-level shfl reduce over lane&7.
    vf4 kreg[8];
    vf4 v0;
    if (wv == 0) v0 = x4[lane];           // field 0: copy only (not a key)
#pragma unroll
    for (int j = 0; j < 8; ++j) {
      kreg[j] = x4[(wv * 8 + j + 1) * 64 + lane];
    }
    if (wv == 0) __builtin_nontemporal_store(v0, &o4[lane]);
#pragma unroll
    for (int j = 0; j < 8; ++j) {
      const int c = wv * 8 + j;           // key index; field f = c+1
      const vf4 v = kreg[j];
      __builtin_nontemporal_store(v, &o4[(c + 1) * 64 + lane]);
      float p = v.x * wq.x + v.y * wq.y + v.z * wq.z + v.w * wq.w;
      p += __shfl_xor(p, 1);
      p += __shfl_xor(p, 2);
      p += __shfl_xor(p, 4);
      if ((lane & 7) == 0) att_t[c * 9 + (lane >> 3)] = p * 0.03125f;
    }
    // Pin kreg: value becomes opaque -> stays resident in VGPRs through
    // phase C (no remat; round 13: VGPR 36 = kreg+wq exactly, no scratch).
#pragma unroll
    for (int j = 0; j < 8; ++j) {
      asm volatile("" : "+v"(kreg[j]));
    }
    __syncthreads();

    // ---- entmax-1.5 via Newton on f(tau) = sum clip(X-tau)^2 - 1 (convex,
    //      decreasing, |f'| >= 2 near root; tau0 = mx-1 has f >= 0; monotone
    //      convergence to the same fp32 fixed point as the reference's
    //      50-iter bisection — verified rounds 9-13, absmax unchanged).
    //      WAVE 0 ONLY (round 12): lane = h*8+kk, 8 c's per lane.
    if (wv == 0) {
      const int h  = lane >> 3;
      const int kk = lane & 7;
      float X[8];
#pragma unroll
      for (int j = 0; j < 8; ++j) X[j] = att_t[(kk * 8 + j) * 9 + h];

      float mx = X[0];
#pragma unroll
      for (int j = 1; j < 8; ++j) mx = fmaxf(mx, X[j]);
      mx = fmaxf(mx, __shfl_xor(mx, 1));
      mx = fmaxf(mx, __shfl_xor(mx, 2));
      mx = fmaxf(mx, __shfl_xor(mx, 4));

      float tau = mx - 1.0f;            // f(tau0) >= 0 (largest clip term = 1)
      for (int it = 0; it < 16; ++it) {
        float s2 = 0.f, s1 = 0.f;
#pragma unroll
        for (int j = 0; j < 8; ++j) {
          const float t = fmaxf(X[j] - tau, 0.f);
          s2 += t * t;
          s1 += t;
        }
        s2 += __shfl_xor(s2, 1); s1 += __shfl_xor(s1, 1);
        s2 += __shfl_xor(s2, 2); s1 += __shfl_xor(s1, 2);
        s2 += __shfl_xor(s2, 4); s1 += __shfl_xor(s1, 4);
        const float delta = (s2 - 1.0f) / (2.0f * fmaxf(s1, 1e-30f));
        const float ntau = tau + delta;
        if (__all(ntau == tau)) break;   // fp32 fixed point reached
        tau = ntau;
      }

      float s = 0.f;
      float p[8];
#pragma unroll
      for (int j = 0; j < 8; ++j) {
        const float t = fmaxf(X[j] - tau, 0.f);
        p[j] = t * t;
        s += p[j];
      }
      s += __shfl_xor(s, 1);
      s += __shfl_xor(s, 2);
      s += __shfl_xor(s, 4);
      const float inv = 1.0f / s;
      const float* __restrict__ vrow = vals + h * kNC + kk * 8;   // L2-hot
#pragma unroll
      for (int j = 0; j < 8; ++j) {
        cw[(kk * 8 + j) * kNH + h] = p[j] * inv * vrow[j];
      }
    }
    __syncthreads();   // publish cw (wave 0) to all waves

    // ---- phase C: 2 passes of 4 heads through the reused 32 KB part buffer.
    //      Per pass: per-wave partials from register-resident keys ->
    //      part[wv] -> barrier -> 512-thread scalar sum of 8 slots + __expf
    //      + NT store. cw4[c*2+hh] = heads 4hh..4hh+3 of key c (broadcast).
#pragma unroll
    for (int hh = 0; hh < 2; ++hh) {
      vf4 a0 = {0.f, 0.f, 0.f, 0.f};
      vf4 a1 = {0.f, 0.f, 0.f, 0.f};
      vf4 a2 = {0.f, 0.f, 0.f, 0.f};
      vf4 a3 = {0.f, 0.f, 0.f, 0.f};
#pragma unroll
      for (int j = 0; j < 8; ++j) {
        const vf4 kv = kreg[j];
        const vf4 ca = cw4[(wv * 8 + j) * 2 + hh];
        a0 += ca.x * kv;
        a1 += ca.y * kv;
        a2 += ca.z * kv;
        a3 += ca.w * kv;
      }
      part[wv * 256 + 0 * 64 + lane] = a0;   // lane-consecutive b128, conflict-free
      part[wv * 256 + 1 * 64 + lane] = a1;
      part[wv * 256 + 2 * 64 + lane] = a2;
      part[wv * 256 + 3 * 64 + lane] = a3;
      __syncthreads();
#pragma unroll
      for (int oo = 0; oo < 2; ++oo) {
        const int o = oo * 512 + tid;        // o = head4*256 + e within this pass
        float s = partf[o];
#pragma unroll
        for (int sl = 1; sl < 8; ++sl) s += partf[sl * 1024 + o];
        __builtin_nontemporal_store(__expf(s), &orow[kXRow + hh * 1024 + o]);
      }
      if (hh == 0) __syncthreads();          // protect part reuse by pass 2
      // after hh==1: next write of part is g+1's hh0, which sits behind
      // g+1's phase-A barrier -> laggards' partf reads here are safe.
    }
  }
}

}  // namespace

extern "C" void kernel_launch(void* const* d_in, const int* in_sizes, int n_in,
                              void* d_out, int out_size, void* d_ws, size_t ws_size,
                              hipStream_t stream) {
  const float* x     = reinterpret_cast<const float*>(d_in[0]);
  const float* bw    = reinterpret_cast<const float*>(d_in[1]);
  const float* query = reinterpret_cast<const float*>(d_in[2]);
  const float* vals  = reinterpret_cast<const float*>(d_in[3]);
  float* out = reinterpret_cast<float*>(d_out);
  float* w2  = reinterpret_cast<float*>(d_ws);   // 256 floats of scratch

  hipLaunchKernelGGL(w2_precompute, dim3(32), dim3(256), 0, stream, bw, query, w2);
  hipLaunchKernelGGL(fused_row, dim3(kRows / kRPB), dim3(512), 0, stream, x, w2, vals, out);
}

// Round 15
// 98.637 us; speedup vs baseline: 1.1483x; 1.1483x over previous
//
#include <hip/hip_runtime.h>
#include <math.h>

namespace {

constexpr int kRows = 4096;
constexpr int kNF   = 65;
constexpr int kNE   = 256;
constexpr int kNH   = 8;
constexpr int kNC   = 64;                  // kNF - 1 fields used
constexpr int kXRow = kNF * kNE;           // 16640 floats per x row
constexpr int kORow = (kNF + kNH) * kNE;   // 18688 floats per out row

typedef float vf4 __attribute__((ext_vector_type(4)));  // NT-store-compatible

__device__ __forceinline__ void nt_store4(const float4& v, float4* dst) {
  vf4 t = {v.x, v.y, v.z, v.w};
  __builtin_nontemporal_store(t, reinterpret_cast<vf4*>(dst));
}

// w2[t] = sum_k bw[t*256+k] * query[(t>>5)*256+k].  32 blocks x 256 threads.
__global__ __launch_bounds__(256) void w2_precompute(
    const float* __restrict__ bw, const float* __restrict__ query,
    float* __restrict__ w2) {
  const int o = threadIdx.x >> 5;          // 0..7: which of this block's outputs
  const int l = threadIdx.x & 31;          // 32 lanes per output
  const int t = blockIdx.x * 8 + o;
  const int h = t >> 5;
  const float4* __restrict__ bp =
      reinterpret_cast<const float4*>(bw + (size_t)t * 256 + l * 8);
  const float4* __restrict__ qp =
      reinterpret_cast<const float4*>(query + (size_t)h * 256 + l * 8);
  const float4 b0 = bp[0], b1 = bp[1];
  const float4 q0 = qp[0], q1 = qp[1];
  float acc = b0.x * q0.x + b0.y * q0.y + b0.z * q0.z + b0.w * q0.w
            + b1.x * q1.x + b1.y * q1.y + b1.z * q1.z + b1.w * q1.w;
  acc += __shfl_xor(acc, 1);
  acc += __shfl_xor(acc, 2);
  acc += __shfl_xor(acc, 4);
  acc += __shfl_xor(acc, 8);
  acc += __shfl_xor(acc, 16);
  if (l == 0) w2[t] = acc;
}

// ROUND-12 OPTIMUM (98.7 us), restored verbatim after rounds 13/14 probes:
// one block = one row, 512 threads = 8 waves; wave wv owns keys c=8wv..8wv+7
// (kreg[8]); entmax wave-0-only Newton (+publish barrier); 2-pass phase C;
// NT stores for all out writes; no min-waves hints.
// Session ledger: spill-free (WRITE=299 MB exact), FETCH=133 MB (L3 retains
// most of the x re-read), 93% of the 579 MB / 6.3 TB/s copy-equivalent
// ceiling. Refuted variants: min-waves hints (spill, r3-5), 256-thr blocks
// (r10), persistent blocks (r11), kreg pin (r13 neutral), 2-row blocks (r14).
__global__ __launch_bounds__(512) void fused_row(
    const float* __restrict__ x, const float* __restrict__ w2g,
    const float* __restrict__ vals, float* __restrict__ out) {
  __shared__ float att_t[kNC * 9];        // [c][h] stride 9: conflict-free gather
  __shared__ float cw[kNC * kNH];         // [c][h], 2 KB
  __shared__ float4 part[8 * 4 * 64];     // [slot][head4][equad], 32 KB (x2 passes)

  const int tid  = threadIdx.x;
  const int wv   = tid >> 6;
  const int lane = tid & 63;
  const int r    = blockIdx.x;

  const float* __restrict__ xrow = x + (size_t)r * kXRow;
  float* __restrict__ orow       = out + (size_t)r * kORow;
  const float4* __restrict__ x4  = reinterpret_cast<const float4*>(xrow);
  float4* __restrict__ o4        = reinterpret_cast<float4*>(orow);

  // ---- phase A: issue ALL loads first (9 outstanding vmem per wave), then
  //      copy -> out (NT) + att dot + 3-level shfl reduce over lane&7.
  //      Lane's w2 quad: head h = lane>>3, dims 4*(lane&7)..+3.
  float4 kreg[8];
  const float4 wq = reinterpret_cast<const float4*>(w2g)[lane];
  float4 v0;
  if (wv == 0) v0 = x4[lane];           // field 0: copy only (not a key)
#pragma unroll
  for (int j = 0; j < 8; ++j) {
    kreg[j] = x4[(wv * 8 + j + 1) * 64 + lane];
  }
  if (wv == 0) nt_store4(v0, &o4[lane]);
#pragma unroll
  for (int j = 0; j < 8; ++j) {
    const int c = wv * 8 + j;           // key index; field f = c+1
    const float4 v = kreg[j];
    nt_store4(v, &o4[(c + 1) * 64 + lane]);
    float p = v.x * wq.x + v.y * wq.y + v.z * wq.z + v.w * wq.w;
    p += __shfl_xor(p, 1);
    p += __shfl_xor(p, 2);
    p += __shfl_xor(p, 4);
    if ((lane & 7) == 0) att_t[c * 9 + (lane >> 3)] = p * 0.03125f;
  }
  __syncthreads();

  // ---- entmax-1.5 via Newton on f(tau) = sum clip(X-tau)^2 - 1 (convex,
  //      decreasing, |f'| >= 2 near root; tau0 = mx-1 has f >= 0; monotone
  //      convergence to the same fp32 fixed point as the reference's 50-iter
  //      bisection — verified rounds 9-14, absmax unchanged). WAVE 0 ONLY:
  //      lane = h*8+kk, 8 c's per lane; cw published via the barrier below.
  if (wv == 0) {
    const int h  = lane >> 3;
    const int kk = lane & 7;
    float X[8];
#pragma unroll
    for (int j = 0; j < 8; ++j) X[j] = att_t[(kk * 8 + j) * 9 + h];

    float mx = X[0];
#pragma unroll
    for (int j = 1; j < 8; ++j) mx = fmaxf(mx, X[j]);
    mx = fmaxf(mx, __shfl_xor(mx, 1));
    mx = fmaxf(mx, __shfl_xor(mx, 2));
    mx = fmaxf(mx, __shfl_xor(mx, 4));

    float tau = mx - 1.0f;            // f(tau0) >= 0 (largest clip term = 1)
    for (int it = 0; it < 16; ++it) {
      float s2 = 0.f, s1 = 0.f;
#pragma unroll
      for (int j = 0; j < 8; ++j) {
        const float t = fmaxf(X[j] - tau, 0.f);
        s2 += t * t;
        s1 += t;
      }
      s2 += __shfl_xor(s2, 1); s1 += __shfl_xor(s1, 1);
      s2 += __shfl_xor(s2, 2); s1 += __shfl_xor(s1, 2);
      s2 += __shfl_xor(s2, 4); s1 += __shfl_xor(s1, 4);
      const float delta = (s2 - 1.0f) / (2.0f * fmaxf(s1, 1e-30f));
      const float ntau = tau + delta;
      if (__all(ntau == tau)) break;   // fp32 fixed point reached
      tau = ntau;
    }

    float s = 0.f;
    float p[8];
#pragma unroll
    for (int j = 0; j < 8; ++j) {
      const float t = fmaxf(X[j] - tau, 0.f);
      p[j] = t * t;
      s += p[j];
    }
    s += __shfl_xor(s, 1);
    s += __shfl_xor(s, 2);
    s += __shfl_xor(s, 4);
    const float inv = 1.0f / s;
    const float* __restrict__ vrow = vals + h * kNC + kk * 8;   // L2-hot
#pragma unroll
    for (int j = 0; j < 8; ++j) {
      cw[(kk * 8 + j) * kNH + h] = p[j] * inv * vrow[j];
    }
  }
  __syncthreads();   // publish cw (wave 0) to all waves

  // ---- phase C: 2 passes of 4 heads through the reused 32 KB part buffer.
  //      Per pass: per-wave partials (keys from kreg; the allocator remats
  //      them as L3-hot global reloads at VGPR ~40 — measured rounds 9/12,
  //      no scratch; pinning them in regs was time-neutral, r13) -> part[wv]
  //      -> barrier -> 512-thread scalar sum of 8 slots + __expf + NT store.
  const float4* __restrict__ cw4 = reinterpret_cast<const float4*>(cw);
  const float* partf             = reinterpret_cast<const float*>(part);
#pragma unroll
  for (int hh = 0; hh < 2; ++hh) {
    float4 a0 = make_float4(0.f, 0.f, 0.f, 0.f);
    float4 a1 = make_float4(0.f, 0.f, 0.f, 0.f);
    float4 a2 = make_float4(0.f, 0.f, 0.f, 0.f);
    float4 a3 = make_float4(0.f, 0.f, 0.f, 0.f);
#pragma unroll
    for (int j = 0; j < 8; ++j) {
      const float4 kv = kreg[j];
      const float4 ca = cw4[(wv * 8 + j) * 2 + hh];
      a0.x += ca.x * kv.x; a0.y += ca.x * kv.y; a0.z += ca.x * kv.z; a0.w += ca.x * kv.w;
      a1.x += ca.y * kv.x; a1.y += ca.y * kv.y; a1.z += ca.y * kv.z; a1.w += ca.y * kv.w;
      a2.x += ca.z * kv.x; a2.y += ca.z * kv.y; a2.z += ca.z * kv.z; a2.w += ca.z * kv.w;
      a3.x += ca.w * kv.x; a3.y += ca.w * kv.y; a3.z += ca.w * kv.z; a3.w += ca.w * kv.w;
    }
    part[wv * 256 + 0 * 64 + lane] = a0;   // lane-consecutive b128, conflict-free
    part[wv * 256 + 1 * 64 + lane] = a1;
    part[wv * 256 + 2 * 64 + lane] = a2;
    part[wv * 256 + 3 * 64 + lane] = a3;
    __syncthreads();
#pragma unroll
    for (int oo = 0; oo < 2; ++oo) {
      const int o = oo * 512 + tid;        // o = head4*256 + e within this pass
      float s = partf[o];
#pragma unroll
      for (int sl = 1; sl < 8; ++sl) s += partf[sl * 1024 + o];
      __builtin_nontemporal_store(__expf(s), &orow[kXRow + hh * 1024 + o]);
    }
    if (hh == 0) __syncthreads();          // protect part reuse by pass 2
  }
}

}  // namespace

extern "C" void kernel_launch(void* const* d_in, const int* in_sizes, int n_in,
                              void* d_out, int out_size, void* d_ws, size_t ws_size,
                              hipStream_t stream) {
  const float* x     = reinterpret_cast<const float*>(d_in[0]);
  const float* bw    = reinterpret_cast<const float*>(d_in[1]);
  const float* query = reinterpret_cast<const float*>(d_in[2]);
  const float* vals  = reinterpret_cast<const float*>(d_in[3]);
  float* out = reinterpret_cast<float*>(d_out);
  float* w2  = reinterpret_cast<float*>(d_ws);   // 256 floats of scratch

  hipLaunchKernelGGL(w2_precompute, dim3(32), dim3(256), 0, stream, bw, query, w2);
  hipLaunchKernelGGL(fused_row, dim3(kRows), dim3(512), 0, stream, x, w2, vals, out);
}